// Round 1
// baseline (66675.922 us; speedup 1.0000x reference)
//
#include <hip/hip_runtime.h>
#include <math.h>

// DenseLSTMForecast: B=256, T=1024, H=128, FUTURE=32.
// Design: 128 persistent WGs x 512 threads, each WG owns 2 batch rows for all
// 1056 steps. No inter-WG communication (autoregressive feedback is row-local).
// Weights pre-transposed to k-major [128][512] in d_ws for coalesced streaming
// (thread g = gate column g); the 1.57 MB weight set stays hot in each XCD L2.

#define TSEQ 1024
#define HH   128
#define TT   1056          // T + FUTURE
#define G4   512           // 4*H gate columns
#define ROWS 2
#define NWG  128

// ws float layout:
//   0*65536 : WT1  [k][g] = W_hh1[g][k]
//   1*65536 : W2a  [k][g] = W_ih2[g][1+k]     (h1 part)
//   2*65536 : W2b  [k][g] = W_hh2[g][k]
//   3*65536 : W3a  [k][g] = W_ih3[g][1+k]     (h1 part)
//   4*65536 : W3b  [k][g] = W_ih3[g][129+k]   (h2 part)
//   5*65536 : W3c  [k][g] = W_hh3[g][k]
//   6*65536 +    0 : xw1[512], +512: xw2[512], +1024: xw3[512]
//   6*65536 + 1536 : bs1[512], +2048: bs2[512], +2560: bs3[512]
#define WOFF_SCAL (6*65536)
#define WS_FLOATS (6*65536 + 3072)

__device__ __forceinline__ float sigmoidf_(float v) {
  return 1.0f / (1.0f + expf(-v));
}

#define LOAD16(dst, srcp) do { \
  const float4* _s = (const float4*)(srcp); \
  float4 _a = _s[0], _b = _s[1], _c = _s[2], _d = _s[3]; \
  (dst)[0]=_a.x; (dst)[1]=_a.y; (dst)[2]=_a.z; (dst)[3]=_a.w; \
  (dst)[4]=_b.x; (dst)[5]=_b.y; (dst)[6]=_b.z; (dst)[7]=_b.w; \
  (dst)[8]=_c.x; (dst)[9]=_c.y; (dst)[10]=_c.z; (dst)[11]=_c.w; \
  (dst)[12]=_d.x; (dst)[13]=_d.y; (dst)[14]=_d.z; (dst)[15]=_d.w; \
} while (0)

#define LOAD8(dst, srcp) do { \
  const float4* _s = (const float4*)(srcp); \
  float4 _a = _s[0], _b = _s[1]; \
  (dst)[0]=_a.x; (dst)[1]=_a.y; (dst)[2]=_a.z; (dst)[3]=_a.w; \
  (dst)[4]=_b.x; (dst)[5]=_b.y; (dst)[6]=_b.z; (dst)[7]=_b.w; \
} while (0)

__global__ void prep_kernel(const float* __restrict__ Wih1, const float* __restrict__ Whh1,
                            const float* __restrict__ bih1, const float* __restrict__ bhh1,
                            const float* __restrict__ Wih2, const float* __restrict__ Whh2,
                            const float* __restrict__ bih2, const float* __restrict__ bhh2,
                            const float* __restrict__ Wih3, const float* __restrict__ Whh3,
                            const float* __restrict__ bih3, const float* __restrict__ bhh3,
                            float* __restrict__ ws) {
  int idx = blockIdx.x * 256 + threadIdx.x;
  if (idx < 6 * 65536) {
    int m = idx >> 16;
    int rem = idx & 65535;
    int k = rem >> 9;        // 0..127
    int g = rem & 511;       // 0..511
    float v;
    switch (m) {
      case 0:  v = Whh1[g * HH + k];         break;
      case 1:  v = Wih2[g * 129 + 1 + k];    break;
      case 2:  v = Whh2[g * HH + k];         break;
      case 3:  v = Wih3[g * 257 + 1 + k];    break;
      case 4:  v = Wih3[g * 257 + 129 + k];  break;
      default: v = Whh3[g * HH + k];         break;
    }
    ws[idx] = v;
  } else if (idx < WS_FLOATS) {
    int r = idx - WOFF_SCAL;
    float v;
    if      (r < 512)  v = Wih1[r];                        // x column, cell1
    else if (r < 1024) v = Wih2[(r - 512) * 129];          // x column, cell2
    else if (r < 1536) v = Wih3[(r - 1024) * 257];         // x column, cell3
    else if (r < 2048) v = bih1[r - 1536] + bhh1[r - 1536];
    else if (r < 2560) v = bih2[r - 2048] + bhh2[r - 2048];
    else               v = bih3[r - 2560] + bhh3[r - 2560];
    ws[idx] = v;
  }
}

__global__ __launch_bounds__(512, 1)
void lstm_kernel(const float* __restrict__ x,
                 const float* __restrict__ Wlin,
                 const float* __restrict__ blin,
                 const float* __restrict__ ws,
                 float* __restrict__ out) {
  __shared__ __align__(16) float h1s[ROWS][HH];
  __shared__ __align__(16) float h2s[ROWS][HH];
  __shared__ __align__(16) float h3s[ROWS][HH];
  __shared__ float gs[ROWS][G4];
  __shared__ float xs[ROWS];
  __shared__ float wl[3 * HH + 2];   // [0]=x coef, [1..384]=h coefs, [385]=b_lin

  const int tid = threadIdx.x;
  const int r0 = blockIdx.x * ROWS;

  for (int i = tid; i < ROWS * HH; i += 512) {
    (&h1s[0][0])[i] = 0.f;
    (&h2s[0][0])[i] = 0.f;
    (&h3s[0][0])[i] = 0.f;
  }
  for (int i = tid; i < 3 * HH + 2; i += 512)
    wl[i] = (i < 3 * HH + 1) ? Wlin[i] : blin[0];
  if (tid < ROWS) xs[tid] = x[(r0 + tid) * TSEQ];
  __syncthreads();

  const float* __restrict__ WT1 = ws + 0 * 65536 + tid;
  const float* __restrict__ W2a = ws + 1 * 65536 + tid;
  const float* __restrict__ W2b = ws + 2 * 65536 + tid;
  const float* __restrict__ W3a = ws + 3 * 65536 + tid;
  const float* __restrict__ W3b = ws + 4 * 65536 + tid;
  const float* __restrict__ W3c = ws + 5 * 65536 + tid;
  const float xw1 = ws[WOFF_SCAL + tid];
  const float xw2 = ws[WOFF_SCAL + 512 + tid];
  const float xw3 = ws[WOFF_SCAL + 1024 + tid];
  const float bs1 = ws[WOFF_SCAL + 1536 + tid];
  const float bs2 = ws[WOFF_SCAL + 2048 + tid];
  const float bs3 = ws[WOFF_SCAL + 2560 + tid];

  float c1 = 0.f, c2 = 0.f, c3 = 0.f;          // used by tid < 256
  const int ar = tid >> 7, aj = tid & (HH - 1);
  const int wid = tid >> 6, lane = tid & 63;

  for (int t = 0; t < TT; ++t) {
    const float x0 = xs[0];
    const float x1 = xs[1];

    // ---------------- cell 1 gates: K = 128 (h1) ----------------
    {
      float a0 = fmaf(xw1, x0, bs1);
      float a1 = fmaf(xw1, x1, bs1);
      #pragma unroll
      for (int kc = 0; kc < HH; kc += 16) {
        float ha[16], hb[16];
        LOAD16(ha, &h1s[0][kc]);
        LOAD16(hb, &h1s[1][kc]);
        #pragma unroll
        for (int j = 0; j < 16; ++j) {
          const float w = WT1[(kc + j) << 9];
          a0 = fmaf(w, ha[j], a0);
          a1 = fmaf(w, hb[j], a1);
        }
      }
      gs[0][tid] = a0;
      gs[1][tid] = a1;
    }
    __syncthreads();
    if (tid < ROWS * HH) {
      const float gi = gs[ar][aj];
      const float gf = gs[ar][aj + HH];
      const float gg = gs[ar][aj + 2 * HH];
      const float go = gs[ar][aj + 3 * HH];
      c1 = sigmoidf_(gf) * c1 + sigmoidf_(gi) * tanhf(gg);
      h1s[ar][aj] = sigmoidf_(go) * tanhf(c1);
    }
    __syncthreads();

    // ---------------- cell 2 gates: K = 256 (h1_new, h2) ----------------
    {
      float a0 = fmaf(xw2, x0, bs2);
      float a1 = fmaf(xw2, x1, bs2);
      #pragma unroll
      for (int kc = 0; kc < HH; kc += 8) {
        float p0[8], p1[8], q0[8], q1[8];
        LOAD8(p0, &h1s[0][kc]);
        LOAD8(p1, &h1s[1][kc]);
        LOAD8(q0, &h2s[0][kc]);
        LOAD8(q1, &h2s[1][kc]);
        #pragma unroll
        for (int j = 0; j < 8; ++j) {
          const float wa = W2a[(kc + j) << 9];
          const float wb = W2b[(kc + j) << 9];
          a0 = fmaf(wa, p0[j], fmaf(wb, q0[j], a0));
          a1 = fmaf(wa, p1[j], fmaf(wb, q1[j], a1));
        }
      }
      gs[0][tid] = a0;
      gs[1][tid] = a1;
    }
    __syncthreads();
    if (tid < ROWS * HH) {
      const float gi = gs[ar][aj];
      const float gf = gs[ar][aj + HH];
      const float gg = gs[ar][aj + 2 * HH];
      const float go = gs[ar][aj + 3 * HH];
      c2 = sigmoidf_(gf) * c2 + sigmoidf_(gi) * tanhf(gg);
      h2s[ar][aj] = sigmoidf_(go) * tanhf(c2);
    }
    __syncthreads();

    // ---------------- cell 3 gates: K = 384 (h1_new, h2_new, h3) ----------------
    {
      float a0 = fmaf(xw3, x0, bs3);
      float a1 = fmaf(xw3, x1, bs3);
      #pragma unroll
      for (int kc = 0; kc < HH; kc += 8) {
        float p0[8], p1[8], q0[8], q1[8], s0[8], s1[8];
        LOAD8(p0, &h1s[0][kc]);
        LOAD8(p1, &h1s[1][kc]);
        LOAD8(q0, &h2s[0][kc]);
        LOAD8(q1, &h2s[1][kc]);
        LOAD8(s0, &h3s[0][kc]);
        LOAD8(s1, &h3s[1][kc]);
        #pragma unroll
        for (int j = 0; j < 8; ++j) {
          const float wa = W3a[(kc + j) << 9];
          const float wb = W3b[(kc + j) << 9];
          const float wc = W3c[(kc + j) << 9];
          a0 = fmaf(wa, p0[j], fmaf(wb, q0[j], fmaf(wc, s0[j], a0)));
          a1 = fmaf(wa, p1[j], fmaf(wb, q1[j], fmaf(wc, s1[j], a1)));
        }
      }
      gs[0][tid] = a0;
      gs[1][tid] = a1;
    }
    __syncthreads();
    if (tid < ROWS * HH) {
      const float gi = gs[ar][aj];
      const float gf = gs[ar][aj + HH];
      const float gg = gs[ar][aj + 2 * HH];
      const float go = gs[ar][aj + 3 * HH];
      c3 = sigmoidf_(gf) * c3 + sigmoidf_(gi) * tanhf(gg);
      h3s[ar][aj] = sigmoidf_(go) * tanhf(c3);
    }
    __syncthreads();

    // ---------------- linear head + next-x ----------------
    if (wid < ROWS) {
      const int r = wid;
      float acc = 0.f;
      #pragma unroll
      for (int j0 = 0; j0 < HH; j0 += 64) {
        const int j = j0 + lane;
        acc += wl[1 + j] * h1s[r][j]
             + wl[1 + HH + j] * h2s[r][j]
             + wl[1 + 2 * HH + j] * h3s[r][j];
      }
      #pragma unroll
      for (int off = 32; off > 0; off >>= 1)
        acc += __shfl_down(acc, off, 64);
      if (lane == 0) {
        const float o = acc + fmaf(wl[0], xs[r], wl[3 * HH + 1]);
        out[(size_t)(r0 + r) * TT + t] = o;
        xs[r] = (t + 1 < TSEQ) ? x[(r0 + r) * TSEQ + (t + 1)] : o;
      }
    }
    __syncthreads();
  }
}

extern "C" void kernel_launch(void* const* d_in, const int* in_sizes, int n_in,
                              void* d_out, int out_size, void* d_ws, size_t ws_size,
                              hipStream_t stream) {
  const float* x    = (const float*)d_in[0];
  const float* Wih1 = (const float*)d_in[1];
  const float* Whh1 = (const float*)d_in[2];
  const float* bih1 = (const float*)d_in[3];
  const float* bhh1 = (const float*)d_in[4];
  const float* Wih2 = (const float*)d_in[5];
  const float* Whh2 = (const float*)d_in[6];
  const float* bih2 = (const float*)d_in[7];
  const float* bhh2 = (const float*)d_in[8];
  const float* Wih3 = (const float*)d_in[9];
  const float* Whh3 = (const float*)d_in[10];
  const float* bih3 = (const float*)d_in[11];
  const float* bhh3 = (const float*)d_in[12];
  const float* Wlin = (const float*)d_in[13];
  const float* blin = (const float*)d_in[14];
  float* ws = (float*)d_ws;
  float* out = (float*)d_out;

  prep_kernel<<<WS_FLOATS / 256, 256, 0, stream>>>(
      Wih1, Whh1, bih1, bhh1, Wih2, Whh2, bih2, bhh2,
      Wih3, Whh3, bih3, bhh3, ws);
  lstm_kernel<<<NWG, 512, 0, stream>>>(x, Wlin, blin, ws, out);
}